// Round 1
// baseline (262.089 us; speedup 1.0000x reference)
//
#include <hip/hip_runtime.h>

#define BGR 8
#define VG  20000
#define NK  128
#define ND  128

typedef float f32x4 __attribute__((ext_vector_type(4)));
typedef short bf16x8 __attribute__((ext_vector_type(8)));

// fp32 -> bf16 bits, round-to-nearest-even
__device__ __forceinline__ short bf16r(float f) {
    union { float f; unsigned u; } c; c.f = f;
    unsigned r = (c.u + 0x7FFFu + ((c.u >> 16) & 1u)) >> 16;
    return (short)r;
}

// ---------------------------------------------------------------------------
// Kernel 1: x_spec[g][k][d] += sum_v E[v,k]*m[v]*x[v,d]  (per 320-v chunk)
// Contraction dim v is the row dim of both operands -> transpose-stage 32-v
// slabs into LDS (layout [chan][v], stride 40 elems = 80B, 16B-aligned rows).
// ---------------------------------------------------------------------------
#define VC 320
#define S1 40

__global__ __launch_bounds__(256) void k_spec(const float* __restrict__ x,
                                              const float* __restrict__ mass,
                                              const float* __restrict__ evecs,
                                              float* __restrict__ xs) {
    const int g     = blockIdx.y;
    const int chunk = blockIdx.x;
    const int v0    = chunk * VC;
    const int rounds = (VG - v0 < VC ? VG - v0 : VC) >> 5;  // all chunks are multiples of 32

    const float* xg = x     + (size_t)g * VG * ND;
    const float* eg = evecs + (size_t)g * VG * NK;
    const float* mg = mass  + (size_t)g * VG;

    __shared__ short At[NK * S1];  // [k_eig][v]
    __shared__ short Bt[ND * S1];  // [d][v]

    const int tid = threadIdx.x;
    const int l   = tid & 63;
    const int w   = tid >> 6;
    const int lo  = l & 15, hi = l >> 4;
    const int r0  = (w & 1) * 64, c0 = (w >> 1) * 64;

    f32x4 acc[4][4] = {};

    for (int r = 0; r < rounds; ++r) {
        const int vb = v0 + r * 32;
        // stage 32 rows x 128 chans of both matrices, transposed, fp32->bf16
#pragma unroll
        for (int it = 0; it < 8; ++it) {
            const int v = it * 4 + w;                 // 0..31
            const float  m  = mg[vb + v];
            const float2 xv = *(const float2*)(xg + (size_t)(vb + v) * ND + 2 * l);
            const float2 ev = *(const float2*)(eg + (size_t)(vb + v) * NK + 2 * l);
            Bt[(2 * l + 0) * S1 + v] = bf16r(xv.x * m);
            Bt[(2 * l + 1) * S1 + v] = bf16r(xv.y * m);
            At[(2 * l + 0) * S1 + v] = bf16r(ev.x);
            At[(2 * l + 1) * S1 + v] = bf16r(ev.y);
        }
        __syncthreads();

        bf16x8 af[4], bfv[4];
#pragma unroll
        for (int i = 0; i < 4; ++i)
            af[i] = *(const bf16x8*)(At + (r0 + 16 * i + lo) * S1 + hi * 8);
#pragma unroll
        for (int j = 0; j < 4; ++j)
            bfv[j] = *(const bf16x8*)(Bt + (c0 + 16 * j + lo) * S1 + hi * 8);
#pragma unroll
        for (int i = 0; i < 4; ++i)
#pragma unroll
            for (int j = 0; j < 4; ++j)
                acc[i][j] = __builtin_amdgcn_mfma_f32_16x16x32_bf16(af[i], bfv[j], acc[i][j], 0, 0, 0);
        __syncthreads();
    }

    float* og = xs + (size_t)g * NK * ND;
#pragma unroll
    for (int i = 0; i < 4; ++i)
#pragma unroll
        for (int j = 0; j < 4; ++j)
#pragma unroll
            for (int t = 0; t < 4; ++t) {
                const int kk = r0 + 16 * i + hi * 4 + t;   // C row = (lane>>4)*4+reg
                const int dd = c0 + 16 * j + lo;           // C col = lane&15
                atomicAdd(og + kk * ND + dd, acc[i][j][t]);
            }
}

// ---------------------------------------------------------------------------
// Kernel 2: Yt[g][d][k] = bf16( exp(-evals[g,k]*max(t[d],1e-8)) * xs[g][k][d] )
// (transposed so GEMM2 has both operands k-contiguous)
// ---------------------------------------------------------------------------
__global__ __launch_bounds__(256) void k_coef(const float* __restrict__ xs,
                                              const float* __restrict__ evals,
                                              const float* __restrict__ dt,
                                              short* __restrict__ Yt) {
    const int gid = blockIdx.x * 256 + threadIdx.x;   // 0 .. 8*128*128-1
    const int g = gid >> 14;
    const int d = (gid >> 7) & 127;
    const int k = gid & 127;
    const float t   = fmaxf(dt[d], 1e-8f);
    const float lam = evals[g * NK + k];
    const float v   = xs[(size_t)g * NK * ND + k * ND + d];
    Yt[gid] = bf16r(__expf(-lam * t) * v);
}

// ---------------------------------------------------------------------------
// Kernel 3: out[v,d] = sum_k E[v,k] * Yt[g][d][k]   (m97-style, K=128 staged once)
// ---------------------------------------------------------------------------
#define S2 128  // no pad: 2 tiles x 32KB = 64KB LDS exactly

__global__ __launch_bounds__(256) void k_out(const float* __restrict__ evecs,
                                             const short* __restrict__ Yt,
                                             float* __restrict__ out) {
    const int g     = blockIdx.y;
    const int chunk = blockIdx.x;               // 157 chunks: 156 full + one 32-row tail
    const int v0    = chunk * 128;
    const int rows  = (VG - v0 < 128) ? (VG - v0) : 128;

    const float* eg = evecs + (size_t)g * VG * NK;
    float*       og = out   + (size_t)g * VG * ND;
    const short* yg = Yt    + (size_t)g * ND * NK;

    __shared__ short As[128 * S2];  // E tile   [v][k] bf16
    __shared__ short Bs[128 * S2];  // Yt tile  [d][k] bf16

    const int tid = threadIdx.x;
#pragma unroll
    for (int it = 0; it < 16; ++it) {
        const int id = it * 256 + tid;
        const int v  = id >> 5;          // 0..127 (row of A, also row d of B)
        const int c4 = id & 31;          // 32 * 4-elem groups
        const int vc = v < rows ? v : rows - 1;  // clamp tail OOB reads
        const float4 e4 = *(const float4*)(eg + (size_t)(v0 + vc) * NK + 4 * c4);
        short4 p;
        p.x = bf16r(e4.x); p.y = bf16r(e4.y); p.z = bf16r(e4.z); p.w = bf16r(e4.w);
        *(short4*)(As + v * S2 + 4 * c4) = p;
        *(uint2*)(Bs + v * S2 + 4 * c4) = *(const uint2*)(yg + v * NK + 4 * c4);
    }
    __syncthreads();

    const int l  = tid & 63;
    const int w  = tid >> 6;
    const int lo = l & 15, hi = l >> 4;
    const int r0 = (w & 1) * 64, c0 = (w >> 1) * 64;

    f32x4 acc[4][4] = {};
#pragma unroll
    for (int ks = 0; ks < 4; ++ks) {
        const int k0 = ks * 32;
        bf16x8 af[4], bfv[4];
#pragma unroll
        for (int i = 0; i < 4; ++i)
            af[i] = *(const bf16x8*)(As + (r0 + 16 * i + lo) * S2 + k0 + hi * 8);
#pragma unroll
        for (int j = 0; j < 4; ++j)
            bfv[j] = *(const bf16x8*)(Bs + (c0 + 16 * j + lo) * S2 + k0 + hi * 8);
#pragma unroll
        for (int i = 0; i < 4; ++i)
#pragma unroll
            for (int j = 0; j < 4; ++j)
                acc[i][j] = __builtin_amdgcn_mfma_f32_16x16x32_bf16(af[i], bfv[j], acc[i][j], 0, 0, 0);
    }

#pragma unroll
    for (int i = 0; i < 4; ++i)
#pragma unroll
        for (int j = 0; j < 4; ++j)
#pragma unroll
            for (int t = 0; t < 4; ++t) {
                const int vv = r0 + 16 * i + hi * 4 + t;
                if (vv < rows)
                    og[(size_t)(v0 + vv) * ND + c0 + 16 * j + lo] = acc[i][j][t];
            }
}

extern "C" void kernel_launch(void* const* d_in, const int* in_sizes, int n_in,
                              void* d_out, int out_size, void* d_ws, size_t ws_size,
                              hipStream_t stream) {
    const float* x     = (const float*)d_in[0];
    const float* mass  = (const float*)d_in[1];
    const float* evals = (const float*)d_in[2];
    const float* evecs = (const float*)d_in[3];
    const float* dt    = (const float*)d_in[4];
    // d_in[5] = batch (unused: equal-sized graphs), d_in[6] = bs (compile-time 8)
    float* out = (float*)d_out;

    float* xs = (float*)d_ws;                                        // 8*128*128 fp32 = 512KB
    short* Yt = (short*)((char*)d_ws + (size_t)BGR * NK * ND * 4);   // 8*128*128 bf16 = 256KB

    hipMemsetAsync(d_ws, 0, (size_t)BGR * NK * ND * sizeof(float), stream);

    k_spec<<<dim3((VG + VC - 1) / VC, BGR), 256, 0, stream>>>(x, mass, evecs, xs);
    k_coef<<<(BGR * NK * ND) / 256, 256, 0, stream>>>(xs, evals, dt, Yt);
    k_out<<<dim3((VG + 127) / 128, BGR), 256, 0, stream>>>(evecs, Yt, out);
}